// Round 3
// baseline (294.297 us; speedup 1.0000x reference)
//
#include <hip/hip_runtime.h>
#include <hip/hip_bf16.h>

// GroupContrast loss. Per-row reductions instead of the 8192x8192 logits:
//   main pass:   sE_i = sum_{j != i} exp(100*acc_ij - 100)      (dense, MFMA)
//   group pass:  sP_i = sum_pos exp(..), sA_i = sum_pos acc     (sparse, ~1% of pairs)
//   (group-pass acc is bitwise-identical to main-pass acc: same MFMA chain)
//   final:  Q = sE - sP;  Z = sP/pc + Q/nc;
//           mlpp = 100*sA/pc - 100 - log(pc) - log(Z);  loss = -T*mean_valid.
// LDS tiles are unpadded (40960 B -> 4 blocks/CU) with XOR swizzle
// (int4 col q stored at q ^ (row&7)) -> 2-way banks on ds_read_b128 (free).

#define N_ROWS 8192
#define D_PAD 320
#define NG 100
#define TEMP 0.01f
#define NSPLIT 32
#define JCHUNK (N_ROWS / NSPLIT)   // 256
#define LOG2E100 144.2695041f      // 100 * log2(e)

typedef short short8v __attribute__((ext_vector_type(8)));
typedef float float4v __attribute__((ext_vector_type(4)));

// ---------- setup: cast x -> bf16[8192][320], W1/W2 -> bf16 Wt[320][320], hist ----------
__global__ __launch_bounds__(256) void setup_kernel(
    const float* __restrict__ x, const float* __restrict__ W1,
    const float* __restrict__ W2, const int* __restrict__ labels,
    __hip_bfloat16* __restrict__ xb, __hip_bfloat16* __restrict__ w1t,
    __hip_bfloat16* __restrict__ w2t, int* __restrict__ counts)
{
  __shared__ int hc[NG + 1];
  int b = blockIdx.x, tid = threadIdx.x;
  if (b < 10240) {                       // cast x (8192*320/256 blocks)
    int idx = b * 256 + tid;
    int m = idx / D_PAD, k = idx - m * D_PAD;
    float v = (k < 300) ? x[(size_t)m * 300 + k] : 0.0f;
    xb[idx] = __float2bfloat16(v);
  } else if (b < 11040) {                // cast+transpose W1 (400) / W2 (400)
    int isW2 = (b >= 10640);
    int idx = (b - (isW2 ? 10640 : 10240)) * 256 + tid;
    const float* W = isW2 ? W2 : W1;
    __hip_bfloat16* dst = isW2 ? w2t : w1t;
    int n = idx / D_PAD, k = idx - n * D_PAD;
    float v = (n < 300 && k < 300) ? W[(size_t)k * 300 + n] : 0.0f;
    dst[idx] = __float2bfloat16(v);
  } else {                               // histogram, 32 blocks x 256 rows
    if (tid <= NG) hc[tid] = 0;
    __syncthreads();
    int row = (b - 11040) * 256 + tid;
    atomicAdd(&hc[labels[row]], 1);
    __syncthreads();
    if (tid <= NG && hc[tid] > 0) atomicAdd(&counts[tid], hc[tid]);
  }
}

// ---------- bf16 MFMA GEMM: C = act(A @ Wt^T + bias), 64x64 tiles ----------
__global__ __launch_bounds__(256, 4) void mlp_gemm_kernel(
    const __hip_bfloat16* __restrict__ Ab, const __hip_bfloat16* __restrict__ Wt,
    const float* __restrict__ bias, void* __restrict__ Cout, int mode)
{
  __shared__ __align__(16) short Bs[64 * D_PAD];
  const short* As = (const short*)Ab;
  int tid = threadIdx.x;
  int lane = tid & 63, wave = tid >> 6;
  int g = lane >> 4, lc = lane & 15, sw = lc & 7;
  int i0 = blockIdx.x * 64;
  int n0 = blockIdx.y * 64;

  {
    const int4* src = (const int4*)Wt;
    int4* dst = (int4*)Bs;
#pragma unroll
    for (int t = 0; t < 10; ++t) {
      int e = tid + t * 256;
      int r = e / 40, q = e - r * 40;
      dst[r * 40 + (q ^ (r & 7))] = src[(size_t)(n0 + r) * 40 + q];
    }
  }
  short8v afr[10];
  {
    const short* ap = As + (size_t)(i0 + wave * 16 + lc) * D_PAD + g * 8;
#pragma unroll
    for (int kk = 0; kk < 10; ++kk) afr[kk] = *(const short8v*)(ap + kk * 32);
  }
  __syncthreads();
  for (int js = 0; js < 4; ++js) {
    float4v acc = {0.f, 0.f, 0.f, 0.f};
    const short* rowp = Bs + (js * 16 + lc) * D_PAD;
#pragma unroll
    for (int kk = 0; kk < 10; ++kk) {
      short8v bf = *(const short8v*)(rowp + (((g + 4 * kk) ^ sw) << 3));
      acc = __builtin_amdgcn_mfma_f32_16x16x32_bf16(afr[kk], bf, acc, 0, 0, 0);
    }
    int n = n0 + js * 16 + lc;
    float bv = (n < 300) ? bias[n] : 0.0f;
#pragma unroll
    for (int r = 0; r < 4; ++r) {
      int m = i0 + wave * 16 + g * 4 + r;
      float v = acc[r] + bv;
      if (mode == 0) {
        v = fmaxf(v, 0.0f);
        ((__hip_bfloat16*)Cout)[(size_t)m * D_PAD + n] = __float2bfloat16(v);
      } else {
        ((float*)Cout)[(size_t)m * D_PAD + n] = v;
      }
    }
  }
}

// ---------- row L2-normalize (fp32 [8192][320], pads=0) -> bf16 ----------
__global__ __launch_bounds__(256) void rownorm_kernel(
    const float* __restrict__ H, __hip_bfloat16* __restrict__ F)
{
  int wave = threadIdx.x >> 6, lane = threadIdx.x & 63;
  int row = blockIdx.x * 4 + wave;
  const float* h = H + (size_t)row * D_PAD;
  float v[5];
  float ss = 0.f;
  for (int t = 0; t < 5; ++t) { v[t] = h[lane + t * 64]; ss += v[t] * v[t]; }
  for (int m = 1; m < 64; m <<= 1) ss += __shfl_xor(ss, m, 64);
  float inv = rsqrtf(ss);
  for (int t = 0; t < 5; ++t)
    F[(size_t)row * D_PAD + lane + t * 64] = __float2bfloat16(v[t] * inv);
}

// ---------- sparse per-group pass: sP_i, sA_i over same-label pairs ----------
__global__ __launch_bounds__(256) void group_kernel(
    const __hip_bfloat16* __restrict__ Fb, const int* __restrict__ labels,
    float* __restrict__ sPar, float* __restrict__ sAar)
{
  __shared__ __align__(16) short Bs[64 * D_PAD];
  __shared__ int memb[256];
  __shared__ int cnt;
  const short* Fs = (const short*)Fb;
  int tid = threadIdx.x;
  int lane = tid & 63, wave = tid >> 6;
  int g = lane >> 4, lc = lane & 15, sw = lc & 7;
  int grp = blockIdx.x + 1;
  if (tid == 0) cnt = 0;
  __syncthreads();
  for (int i = tid; i < N_ROWS; i += 256)
    if (labels[i] == grp) { int p = atomicAdd(&cnt, 1); if (p < 256) memb[p] = i; }
  __syncthreads();
  int c = cnt > 256 ? 256 : cnt;
  int nt = (c + 63) >> 6;
  for (int it = 0; it < nt; ++it) {
    short8v afr[10];
    {
      int islot = it * 64 + wave * 16 + lc;
      int arow = memb[islot < c ? islot : 0];
      const short* ap = Fs + (size_t)arow * D_PAD + g * 8;
#pragma unroll
      for (int kk = 0; kk < 10; ++kk) afr[kk] = *(const short8v*)(ap + kk * 32);
    }
    int iglobr[4]; bool ivalid[4];
    for (int r = 0; r < 4; ++r) {
      int islot = it * 64 + wave * 16 + g * 4 + r;
      ivalid[r] = islot < c;
      iglobr[r] = memb[islot < c ? islot : 0];
    }
    float sp[4] = {}, sa[4] = {};
    for (int jt = 0; jt < nt; ++jt) {
      __syncthreads();
      {
        const int4* src = (const int4*)Fs;
        int4* dst = (int4*)Bs;
#pragma unroll
        for (int t = 0; t < 10; ++t) {
          int e = tid + t * 256;
          int r = e / 40, q = e - r * 40;
          int jslot = jt * 64 + r;
          int grow = memb[jslot < c ? jslot : 0];
          dst[r * 40 + (q ^ (r & 7))] = src[(size_t)grow * 40 + q];
        }
      }
      __syncthreads();
      for (int js = 0; js < 4; ++js) {
        float4v acc = {0.f, 0.f, 0.f, 0.f};
        const short* rowp = Bs + (js * 16 + lc) * D_PAD;
#pragma unroll
        for (int kk = 0; kk < 10; ++kk) {
          short8v bf = *(const short8v*)(rowp + (((g + 4 * kk) ^ sw) << 3));
          acc = __builtin_amdgcn_mfma_f32_16x16x32_bf16(afr[kk], bf, acc, 0, 0, 0);
        }
        int jslot = jt * 64 + js * 16 + lc;
        bool jv = jslot < c;
        int jglob = memb[jslot < c ? jslot : 0];
#pragma unroll
        for (int r = 0; r < 4; ++r) {
          float a = acc[r];
          float e = exp2f(fmaf(a, LOG2E100, -LOG2E100));
          bool ok = jv && ivalid[r] && (jglob != iglobr[r]);
          sp[r] += ok ? e : 0.f;
          sa[r] += ok ? a : 0.f;
        }
      }
    }
    for (int m = 1; m < 16; m <<= 1)
      for (int r = 0; r < 4; ++r) {
        sp[r] += __shfl_xor(sp[r], m, 64);
        sa[r] += __shfl_xor(sa[r], m, 64);
      }
    if (lc == 0)
      for (int r = 0; r < 4; ++r)
        if (ivalid[r]) { sPar[iglobr[r]] = sp[r]; sAar[iglobr[r]] = sa[r]; }
  }
}

// ---------- dense pairwise: sE only ----------
__global__ __launch_bounds__(256, 4) void pairwise_kernel(
    const __hip_bfloat16* __restrict__ Fb, float* __restrict__ partE)
{
  __shared__ __align__(16) short Bs[64 * D_PAD];
  const short* Fs = (const short*)Fb;
  int tid = threadIdx.x;
  int lane = tid & 63, wave = tid >> 6;
  int g = lane >> 4, lc = lane & 15, sw = lc & 7;
  int i0 = blockIdx.x * 128;
  int split = blockIdx.y;
  int jstart = split * JCHUNK;

  short8v afr[2][10];
  for (int s = 0; s < 2; ++s) {
    const short* ap = Fs + (size_t)(i0 + s * 64 + wave * 16 + lc) * D_PAD + g * 8;
#pragma unroll
    for (int kk = 0; kk < 10; ++kk) afr[s][kk] = *(const short8v*)(ap + kk * 32);
  }
  float sE[2][4] = {};

  for (int jt = 0; jt < JCHUNK / 64; ++jt) {
    int jb = jstart + jt * 64;
    __syncthreads();
    {
      const int4* src = (const int4*)Fs;
      int4* dst = (int4*)Bs;
#pragma unroll
      for (int t = 0; t < 10; ++t) {
        int e = tid + t * 256;
        int r = e / 40, q = e - r * 40;
        dst[r * 40 + (q ^ (r & 7))] = src[(size_t)(jb + r) * 40 + q];
      }
    }
    __syncthreads();
    for (int js = 0; js < 4; ++js) {
      float4v acc0 = {0.f, 0.f, 0.f, 0.f}, acc1 = {0.f, 0.f, 0.f, 0.f};
      const short* rowp = Bs + (js * 16 + lc) * D_PAD;
#pragma unroll
      for (int kk = 0; kk < 10; ++kk) {
        short8v bf = *(const short8v*)(rowp + (((g + 4 * kk) ^ sw) << 3));
        acc0 = __builtin_amdgcn_mfma_f32_16x16x32_bf16(afr[0][kk], bf, acc0, 0, 0, 0);
        acc1 = __builtin_amdgcn_mfma_f32_16x16x32_bf16(afr[1][kk], bf, acc1, 0, 0, 0);
      }
#pragma unroll
      for (int s = 0; s < 2; ++s) {
        float4v acc = s ? acc1 : acc0;
        bool dtile = (jb == i0 + s * 64) && (js == wave);
#pragma unroll
        for (int r = 0; r < 4; ++r) {
          float e = exp2f(fmaf(acc[r], LOG2E100, -LOG2E100));
          // diagonal must be excluded here (cannot be reconstructed later
          // without catastrophic cancellation against the ~1e-30 sums)
          if (dtile && lc == g * 4 + r) e = 0.0f;
          sE[s][r] += e;
        }
      }
    }
  }
  for (int m = 1; m < 16; m <<= 1)
    for (int s = 0; s < 2; ++s)
      for (int r = 0; r < 4; ++r) sE[s][r] += __shfl_xor(sE[s][r], m, 64);
  if (lc == 0)
    for (int s = 0; s < 2; ++s)
      for (int r = 0; r < 4; ++r)
        partE[split * N_ROWS + i0 + s * 64 + wave * 16 + g * 4 + r] = sE[s][r];
}

// ---------- final: per-row combine (32 blocks) + scalar reduce (1 block) ----------
__global__ __launch_bounds__(256) void final_a_kernel(
    const float* __restrict__ partE, const float* __restrict__ sPar,
    const float* __restrict__ sAar, const int* __restrict__ counts,
    const int* __restrict__ labels, float* __restrict__ blk)
{
  int tid = threadIdx.x;
  int i = blockIdx.x * 256 + tid;
  float sE = 0.f;
  for (int s = 0; s < NSPLIT; ++s) sE += partE[s * N_ROWS + i];
  float M = 0.f, V = 0.f;
  int pc = counts[labels[i]] - 1;
  if (pc > 0) {
    float P = sPar[i], A = sAar[i];
    float Q = sE - P;
    float pcf = (float)pc, ncf = (float)(N_ROWS - 1 - pc);
    float Z = P / pcf + Q / ncf;
    M = 100.0f * A / pcf - 100.0f - logf(pcf) - logf(Z);
    V = 1.f;
  }
  __shared__ float rm[256], rv[256];
  rm[tid] = M; rv[tid] = V;
  __syncthreads();
  for (int s2 = 128; s2 > 0; s2 >>= 1) {
    if (tid < s2) { rm[tid] += rm[tid + s2]; rv[tid] += rv[tid + s2]; }
    __syncthreads();
  }
  if (tid == 0) { blk[blockIdx.x] = rm[0]; blk[32 + blockIdx.x] = rv[0]; }
}

__global__ void final_b_kernel(const float* __restrict__ blk, float* __restrict__ out)
{
  int lane = threadIdx.x;   // 64 threads
  float m = (lane < 32) ? blk[lane] : 0.f;
  float v = (lane < 32) ? blk[32 + lane] : 0.f;
  for (int s = 1; s < 32; s <<= 1) { m += __shfl_xor(m, s, 64); v += __shfl_xor(v, s, 64); }
  if (lane == 0) out[0] = (v > 0.f) ? (-TEMP * m / v) : 0.f;
}

extern "C" void kernel_launch(void* const* d_in, const int* in_sizes, int n_in,
                              void* d_out, int out_size, void* d_ws, size_t ws_size,
                              hipStream_t stream)
{
  const float* x  = (const float*)d_in[0];
  const float* W1 = (const float*)d_in[1];
  const float* b1 = (const float*)d_in[2];
  const float* W2 = (const float*)d_in[3];
  const float* b2 = (const float*)d_in[4];
  const int* labels = (const int*)d_in[5];

  char* ws = (char*)d_ws;
  __hip_bfloat16* xb  = (__hip_bfloat16*)(ws);              // 5,242,880
  __hip_bfloat16* fb  = (__hip_bfloat16*)(ws);              // reuses xb (dead after mlp1)
  __hip_bfloat16* h1  = (__hip_bfloat16*)(ws + 5242880);    // 5,242,880
  float*          h2  = (float*)(ws + 10485760);            // 10,485,760
  __hip_bfloat16* w1t = (__hip_bfloat16*)(ws + 20971520);   // 204,800
  __hip_bfloat16* w2t = (__hip_bfloat16*)(ws + 21176320);   // 204,800
  int*         counts = (int*)(ws + 21381120);              // 512
  float*        partE = (float*)(ws + 21381632);            // 1,048,576
  float*        sPar  = (float*)(ws + 22430208);            // 32,768
  float*        sAar  = (float*)(ws + 22462976);            // 32,768
  float*        blk   = (float*)(ws + 22495744);            // 256

  hipMemsetAsync(counts, 0, (NG + 1) * sizeof(int), stream);
  setup_kernel<<<11072, 256, 0, stream>>>(x, W1, W2, labels, xb, w1t, w2t, counts);
  mlp_gemm_kernel<<<dim3(N_ROWS / 64, 5), 256, 0, stream>>>(xb, w1t, b1, h1, 0);
  mlp_gemm_kernel<<<dim3(N_ROWS / 64, 5), 256, 0, stream>>>(h1, w2t, b2, h2, 1);
  rownorm_kernel<<<N_ROWS / 4, 256, 0, stream>>>(h2, fb);
  group_kernel<<<NG, 256, 0, stream>>>(fb, labels, sPar, sAar);
  pairwise_kernel<<<dim3(N_ROWS / 128, NSPLIT), 256, 0, stream>>>(fb, partE);
  final_a_kernel<<<32, 256, 0, stream>>>(partE, sPar, sAar, counts, labels, blk);
  final_b_kernel<<<1, 64, 0, stream>>>(blk, (float*)d_out);
}

// Round 4
// 174.827 us; speedup vs baseline: 1.6834x; 1.6834x over previous
//
#include <hip/hip_runtime.h>
#include <hip/hip_bf16.h>

// GroupContrast loss. Per-row reductions instead of the 8192x8192 logits:
//   main pass:   sE_i = sum_{j != i} exp(100*acc_ij - 100)      (dense, MFMA)
//   group pass:  sP_i = sum_pos exp(..), sA_i = sum_pos acc     (sparse, ~1% of pairs)
//   (group-pass acc is bitwise-identical to main-pass acc: same MFMA chain)
//   final:  Q = sE - sP;  Z = sP/pc + Q/nc;
//           mlpp = 100*sA/pc - 100 - log(pc) - log(Z);  loss = -T*mean_valid.
// MLP (x@W1+b1 -> relu -> @W2+b2 -> rownorm -> bf16 fb) fused into ONE kernel:
// row-independent, so each block owns 64 rows end-to-end; W tiles stream
// through LDS; h2 lives in 80 VGPRs; no fp32 h2 buffer, no separate rownorm.
// LDS tiles unpadded + XOR-swizzled (int4 col q at q^(row&7)): 0 bank conflicts.
// NOTE: pairwise __launch_bounds__ must stay (256,2) — (256,4) caps VGPR at 64
// and spills afr[2][10] to scratch (round-3: 328MB FETCH, 2x slowdown).

#define N_ROWS 8192
#define D_PAD 320
#define NG 100
#define TEMP 0.01f
#define NSPLIT 32
#define JCHUNK (N_ROWS / NSPLIT)   // 256
#define LOG2E100 144.2695041f      // 100 * log2(e)

typedef short short8v __attribute__((ext_vector_type(8)));
typedef float float4v __attribute__((ext_vector_type(4)));

__device__ __forceinline__ short f2bf(float f) {
  union { __hip_bfloat16 h; short s; } u;
  u.h = __float2bfloat16(f);
  return u.s;
}

// ---------- setup: W1/W2 -> bf16 Wt[320 n][320 k] transposed, + histogram ----------
__global__ __launch_bounds__(256) void setup_kernel(
    const float* __restrict__ W1, const float* __restrict__ W2,
    const int* __restrict__ labels,
    __hip_bfloat16* __restrict__ w1t, __hip_bfloat16* __restrict__ w2t,
    int* __restrict__ counts)
{
  __shared__ int hc[NG + 1];
  int b = blockIdx.x, tid = threadIdx.x;
  if (b < 800) {                         // cast+transpose W1 (400) / W2 (400)
    int isW2 = (b >= 400);
    int idx = (b - (isW2 ? 400 : 0)) * 256 + tid;
    const float* W = isW2 ? W2 : W1;
    __hip_bfloat16* dst = isW2 ? w2t : w1t;
    int n = idx / D_PAD, k = idx - n * D_PAD;
    float v = (n < 300 && k < 300) ? W[(size_t)k * 300 + n] : 0.0f;
    dst[idx] = __float2bfloat16(v);
  } else {                               // histogram, 32 blocks x 256 rows
    if (tid <= NG) hc[tid] = 0;
    __syncthreads();
    int row = (b - 800) * 256 + tid;
    atomicAdd(&hc[labels[row]], 1);
    __syncthreads();
    if (tid <= NG && hc[tid] > 0) atomicAdd(&counts[tid], hc[tid]);
  }
}

// ---------- fused MLP + rownorm: x -> fb (bf16, unit rows, padded to 320) ----------
// Block = 64 rows. GEMM1: A=x rows (regs), B=W1t chunks (LDS), h1 -> LDS bf16.
// GEMM2: A=h1 (regs from LDS), B=W2t chunks (LDS), h2 in 80 VGPRs; shuffle-ssq;
// scale; write fb.
__global__ __launch_bounds__(256, 2) void mlp_fused_kernel(
    const float* __restrict__ x, const __hip_bfloat16* __restrict__ w1t,
    const __hip_bfloat16* __restrict__ w2t, const float* __restrict__ b1,
    const float* __restrict__ b2, __hip_bfloat16* __restrict__ fb)
{
  __shared__ __align__(16) short Ws[64 * D_PAD];   // 40960 B, W chunk (swizzled)
  __shared__ __align__(16) short H1[64 * D_PAD];   // 40960 B, h1 tile (swizzled)
  int tid = threadIdx.x;
  int lane = tid & 63, wave = tid >> 6;
  int g = lane >> 4, lc = lane & 15, sw = lc & 7;
  int i0 = blockIdx.x * 64;

  // ---- A-frags from x: rows wave*16+lc, cols kk*32+g*8..+8 (fp32 -> bf16) ----
  short8v afr[10];
  {
    const float* xp = x + (size_t)(i0 + wave * 16 + lc) * 300;
#pragma unroll
    for (int kk = 0; kk < 10; ++kk) {
      int k0 = kk * 32 + g * 8;
      short8v v;
      if (k0 + 8 <= 300) {
        float4 a = *(const float4*)(xp + k0);
        float4 c = *(const float4*)(xp + k0 + 4);
        v[0] = f2bf(a.x); v[1] = f2bf(a.y); v[2] = f2bf(a.z); v[3] = f2bf(a.w);
        v[4] = f2bf(c.x); v[5] = f2bf(c.y); v[6] = f2bf(c.z); v[7] = f2bf(c.w);
      } else if (k0 < 300) {     // k0 == 296: last partial fragment
        float4 a = *(const float4*)(xp + k0);
        v[0] = f2bf(a.x); v[1] = f2bf(a.y); v[2] = f2bf(a.z); v[3] = f2bf(a.w);
        v[4] = 0; v[5] = 0; v[6] = 0; v[7] = 0;
      } else {
        v = short8v{0, 0, 0, 0, 0, 0, 0, 0};
      }
      afr[kk] = v;
    }
  }

  // ---- GEMM1: h1 = relu(x @ W1 + b1) -> H1 (bf16, swizzled) ----
  for (int c = 0; c < 5; ++c) {
    __syncthreads();
    {
      const int4* src = (const int4*)w1t;
      int4* dst = (int4*)Ws;
#pragma unroll
      for (int t = 0; t < 10; ++t) {
        int e = tid + t * 256;
        int r = e / 40, q = e - r * 40;
        dst[r * 40 + (q ^ (r & 7))] = src[(size_t)(c * 64 + r) * 40 + q];
      }
    }
    __syncthreads();
    for (int js = 0; js < 4; ++js) {
      float4v acc = {0.f, 0.f, 0.f, 0.f};
      const short* rowp = Ws + (js * 16 + lc) * D_PAD;
#pragma unroll
      for (int kk = 0; kk < 10; ++kk) {
        short8v bf = *(const short8v*)(rowp + (((g + 4 * kk) ^ sw) << 3));
        acc = __builtin_amdgcn_mfma_f32_16x16x32_bf16(afr[kk], bf, acc, 0, 0, 0);
      }
      int n = c * 64 + js * 16 + lc;
      float bv = (n < 300) ? b1[n] : 0.0f;
#pragma unroll
      for (int r = 0; r < 4; ++r) {
        int row = wave * 16 + g * 4 + r;
        int q = n >> 3;
        H1[row * D_PAD + ((q ^ (row & 7)) << 3) + (n & 7)] =
            f2bf(fmaxf(acc[r] + bv, 0.0f));
      }
    }
  }
  __syncthreads();   // H1 complete

  // ---- h1 A-frags from LDS ----
  short8v hfr[10];
  {
    const short* rp = H1 + (wave * 16 + lc) * D_PAD;
#pragma unroll
    for (int kk = 0; kk < 10; ++kk)
      hfr[kk] = *(const short8v*)(rp + (((g + 4 * kk) ^ sw) << 3));
  }

  // ---- GEMM2: h2 = h1 @ W2 + b2, kept in registers ----
  float4v h2a[5][4];
  for (int c = 0; c < 5; ++c) {
    __syncthreads();
    {
      const int4* src = (const int4*)w2t;
      int4* dst = (int4*)Ws;
#pragma unroll
      for (int t = 0; t < 10; ++t) {
        int e = tid + t * 256;
        int r = e / 40, q = e - r * 40;
        dst[r * 40 + (q ^ (r & 7))] = src[(size_t)(c * 64 + r) * 40 + q];
      }
    }
    __syncthreads();
#pragma unroll
    for (int js = 0; js < 4; ++js) {
      float4v acc = {0.f, 0.f, 0.f, 0.f};
      const short* rowp = Ws + (js * 16 + lc) * D_PAD;
#pragma unroll
      for (int kk = 0; kk < 10; ++kk) {
        short8v bf = *(const short8v*)(rowp + (((g + 4 * kk) ^ sw) << 3));
        acc = __builtin_amdgcn_mfma_f32_16x16x32_bf16(hfr[kk], bf, acc, 0, 0, 0);
      }
      int n = c * 64 + js * 16 + lc;
      float bv = (n < 300) ? b2[n] : 0.0f;
#pragma unroll
      for (int r = 0; r < 4; ++r) acc[r] += bv;   // pad cols: W/b pads=0 -> h2=0
      h2a[c][js] = acc;
    }
  }

  // ---- row ssq (shuffle over the 16 lanes sharing g) + normalize + store ----
  float ssq[4] = {0.f, 0.f, 0.f, 0.f};
#pragma unroll
  for (int c = 0; c < 5; ++c)
#pragma unroll
    for (int js = 0; js < 4; ++js)
#pragma unroll
      for (int r = 0; r < 4; ++r) ssq[r] = fmaf(h2a[c][js][r], h2a[c][js][r], ssq[r]);
  for (int m = 1; m < 16; m <<= 1)
#pragma unroll
    for (int r = 0; r < 4; ++r) ssq[r] += __shfl_xor(ssq[r], m, 64);
  float inv[4];
#pragma unroll
  for (int r = 0; r < 4; ++r) inv[r] = rsqrtf(ssq[r]);
#pragma unroll
  for (int c = 0; c < 5; ++c)
#pragma unroll
    for (int js = 0; js < 4; ++js) {
      int n = c * 64 + js * 16 + lc;
#pragma unroll
      for (int r = 0; r < 4; ++r) {
        int row = i0 + wave * 16 + g * 4 + r;
        fb[(size_t)row * D_PAD + n] = __float2bfloat16(h2a[c][js][r] * inv[r]);
      }
    }
}

// ---------- sparse per-group pass: sP_i, sA_i over same-label pairs ----------
__global__ __launch_bounds__(256) void group_kernel(
    const __hip_bfloat16* __restrict__ Fb, const int* __restrict__ labels,
    float* __restrict__ sPar, float* __restrict__ sAar)
{
  __shared__ __align__(16) short Bs[64 * D_PAD];
  __shared__ int memb[256];
  __shared__ int cnt;
  const short* Fs = (const short*)Fb;
  int tid = threadIdx.x;
  int lane = tid & 63, wave = tid >> 6;
  int g = lane >> 4, lc = lane & 15, sw = lc & 7;
  int grp = blockIdx.x + 1;
  if (tid == 0) cnt = 0;
  __syncthreads();
  for (int i = tid; i < N_ROWS; i += 256)
    if (labels[i] == grp) { int p = atomicAdd(&cnt, 1); if (p < 256) memb[p] = i; }
  __syncthreads();
  int c = cnt > 256 ? 256 : cnt;
  int nt = (c + 63) >> 6;
  for (int it = 0; it < nt; ++it) {
    short8v afr[10];
    {
      int islot = it * 64 + wave * 16 + lc;
      int arow = memb[islot < c ? islot : 0];
      const short* ap = Fs + (size_t)arow * D_PAD + g * 8;
#pragma unroll
      for (int kk = 0; kk < 10; ++kk) afr[kk] = *(const short8v*)(ap + kk * 32);
    }
    int iglobr[4]; bool ivalid[4];
    for (int r = 0; r < 4; ++r) {
      int islot = it * 64 + wave * 16 + g * 4 + r;
      ivalid[r] = islot < c;
      iglobr[r] = memb[islot < c ? islot : 0];
    }
    float sp[4] = {}, sa[4] = {};
    for (int jt = 0; jt < nt; ++jt) {
      __syncthreads();
      {
        const int4* src = (const int4*)Fs;
        int4* dst = (int4*)Bs;
#pragma unroll
        for (int t = 0; t < 10; ++t) {
          int e = tid + t * 256;
          int r = e / 40, q = e - r * 40;
          int jslot = jt * 64 + r;
          int grow = memb[jslot < c ? jslot : 0];
          dst[r * 40 + (q ^ (r & 7))] = src[(size_t)grow * 40 + q];
        }
      }
      __syncthreads();
      for (int js = 0; js < 4; ++js) {
        float4v acc = {0.f, 0.f, 0.f, 0.f};
        const short* rowp = Bs + (js * 16 + lc) * D_PAD;
#pragma unroll
        for (int kk = 0; kk < 10; ++kk) {
          short8v bf = *(const short8v*)(rowp + (((g + 4 * kk) ^ sw) << 3));
          acc = __builtin_amdgcn_mfma_f32_16x16x32_bf16(afr[kk], bf, acc, 0, 0, 0);
        }
        int jslot = jt * 64 + js * 16 + lc;
        bool jv = jslot < c;
        int jglob = memb[jslot < c ? jslot : 0];
#pragma unroll
        for (int r = 0; r < 4; ++r) {
          float a = acc[r];
          float e = exp2f(fmaf(a, LOG2E100, -LOG2E100));
          bool ok = jv && ivalid[r] && (jglob != iglobr[r]);
          sp[r] += ok ? e : 0.f;
          sa[r] += ok ? a : 0.f;
        }
      }
    }
    for (int m = 1; m < 16; m <<= 1)
      for (int r = 0; r < 4; ++r) {
        sp[r] += __shfl_xor(sp[r], m, 64);
        sa[r] += __shfl_xor(sa[r], m, 64);
      }
    if (lc == 0)
      for (int r = 0; r < 4; ++r)
        if (ivalid[r]) { sPar[iglobr[r]] = sp[r]; sAar[iglobr[r]] = sa[r]; }
  }
}

// ---------- dense pairwise: sE only ----------
__global__ __launch_bounds__(256, 2) void pairwise_kernel(
    const __hip_bfloat16* __restrict__ Fb, float* __restrict__ partE)
{
  __shared__ __align__(16) short Bs[64 * D_PAD];
  const short* Fs = (const short*)Fb;
  int tid = threadIdx.x;
  int lane = tid & 63, wave = tid >> 6;
  int g = lane >> 4, lc = lane & 15, sw = lc & 7;
  int i0 = blockIdx.x * 128;
  int split = blockIdx.y;
  int jstart = split * JCHUNK;

  short8v afr[2][10];
  for (int s = 0; s < 2; ++s) {
    const short* ap = Fs + (size_t)(i0 + s * 64 + wave * 16 + lc) * D_PAD + g * 8;
#pragma unroll
    for (int kk = 0; kk < 10; ++kk) afr[s][kk] = *(const short8v*)(ap + kk * 32);
  }
  float sE[2][4] = {};

  for (int jt = 0; jt < JCHUNK / 64; ++jt) {
    int jb = jstart + jt * 64;
    __syncthreads();
    {
      const int4* src = (const int4*)Fs;
      int4* dst = (int4*)Bs;
#pragma unroll
      for (int t = 0; t < 10; ++t) {
        int e = tid + t * 256;
        int r = e / 40, q = e - r * 40;
        dst[r * 40 + (q ^ (r & 7))] = src[(size_t)(jb + r) * 40 + q];
      }
    }
    __syncthreads();
    for (int js = 0; js < 4; ++js) {
      float4v acc0 = {0.f, 0.f, 0.f, 0.f}, acc1 = {0.f, 0.f, 0.f, 0.f};
      const short* rowp = Bs + (js * 16 + lc) * D_PAD;
#pragma unroll
      for (int kk = 0; kk < 10; ++kk) {
        short8v bf = *(const short8v*)(rowp + (((g + 4 * kk) ^ sw) << 3));
        acc0 = __builtin_amdgcn_mfma_f32_16x16x32_bf16(afr[0][kk], bf, acc0, 0, 0, 0);
        acc1 = __builtin_amdgcn_mfma_f32_16x16x32_bf16(afr[1][kk], bf, acc1, 0, 0, 0);
      }
#pragma unroll
      for (int s = 0; s < 2; ++s) {
        float4v acc = s ? acc1 : acc0;
        bool dtile = (jb == i0 + s * 64) && (js == wave);
#pragma unroll
        for (int r = 0; r < 4; ++r) {
          float e = exp2f(fmaf(acc[r], LOG2E100, -LOG2E100));
          // diagonal excluded here (cannot be reconstructed later without
          // catastrophic cancellation against the ~1e-30-scale sums)
          if (dtile && lc == g * 4 + r) e = 0.0f;
          sE[s][r] += e;
        }
      }
    }
  }
  for (int m = 1; m < 16; m <<= 1)
    for (int s = 0; s < 2; ++s)
      for (int r = 0; r < 4; ++r) sE[s][r] += __shfl_xor(sE[s][r], m, 64);
  if (lc == 0)
    for (int s = 0; s < 2; ++s)
      for (int r = 0; r < 4; ++r)
        partE[split * N_ROWS + i0 + s * 64 + wave * 16 + g * 4 + r] = sE[s][r];
}

// ---------- final: per-row combine (32 blocks) + scalar reduce (1 block) ----------
__global__ __launch_bounds__(256) void final_a_kernel(
    const float* __restrict__ partE, const float* __restrict__ sPar,
    const float* __restrict__ sAar, const int* __restrict__ counts,
    const int* __restrict__ labels, float* __restrict__ blk)
{
  int tid = threadIdx.x;
  int i = blockIdx.x * 256 + tid;
  float sE = 0.f;
  for (int s = 0; s < NSPLIT; ++s) sE += partE[s * N_ROWS + i];
  float M = 0.f, V = 0.f;
  int pc = counts[labels[i]] - 1;
  if (pc > 0) {
    float P = sPar[i], A = sAar[i];
    float Q = sE - P;
    float pcf = (float)pc, ncf = (float)(N_ROWS - 1 - pc);
    float Z = P / pcf + Q / ncf;
    M = 100.0f * A / pcf - 100.0f - logf(pcf) - logf(Z);
    V = 1.f;
  }
  __shared__ float rm[256], rv[256];
  rm[tid] = M; rv[tid] = V;
  __syncthreads();
  for (int s2 = 128; s2 > 0; s2 >>= 1) {
    if (tid < s2) { rm[tid] += rm[tid + s2]; rv[tid] += rv[tid + s2]; }
    __syncthreads();
  }
  if (tid == 0) { blk[blockIdx.x] = rm[0]; blk[32 + blockIdx.x] = rv[0]; }
}

__global__ void final_b_kernel(const float* __restrict__ blk, float* __restrict__ out)
{
  int lane = threadIdx.x;   // 64 threads
  float m = (lane < 32) ? blk[lane] : 0.f;
  float v = (lane < 32) ? blk[32 + lane] : 0.f;
  for (int s = 1; s < 32; s <<= 1) { m += __shfl_xor(m, s, 64); v += __shfl_xor(v, s, 64); }
  if (lane == 0) out[0] = (v > 0.f) ? (-TEMP * m / v) : 0.f;
}

extern "C" void kernel_launch(void* const* d_in, const int* in_sizes, int n_in,
                              void* d_out, int out_size, void* d_ws, size_t ws_size,
                              hipStream_t stream)
{
  const float* x  = (const float*)d_in[0];
  const float* W1 = (const float*)d_in[1];
  const float* b1 = (const float*)d_in[2];
  const float* W2 = (const float*)d_in[3];
  const float* b2 = (const float*)d_in[4];
  const int* labels = (const int*)d_in[5];

  char* ws = (char*)d_ws;
  __hip_bfloat16* fb  = (__hip_bfloat16*)(ws);              // 5,242,880
  __hip_bfloat16* w1t = (__hip_bfloat16*)(ws + 5242880);    // 204,800
  __hip_bfloat16* w2t = (__hip_bfloat16*)(ws + 5447680);    // 204,800
  int*         counts = (int*)(ws + 5652480);               // 512
  float*        partE = (float*)(ws + 5652992);             // 1,048,576
  float*        sPar  = (float*)(ws + 6701568);             // 32,768
  float*        sAar  = (float*)(ws + 6734336);             // 32,768
  float*        blk   = (float*)(ws + 6767104);             // 256

  hipMemsetAsync(counts, 0, (NG + 1) * sizeof(int), stream);
  setup_kernel<<<832, 256, 0, stream>>>(W1, W2, labels, w1t, w2t, counts);
  mlp_fused_kernel<<<N_ROWS / 64, 256, 0, stream>>>(x, w1t, w2t, b1, b2, fb);
  group_kernel<<<NG, 256, 0, stream>>>(fb, labels, sPar, sAar);
  pairwise_kernel<<<dim3(N_ROWS / 128, NSPLIT), 256, 0, stream>>>(fb, partE);
  final_a_kernel<<<32, 256, 0, stream>>>(partE, sPar, sAar, counts, labels, blk);
  final_b_kernel<<<1, 64, 0, stream>>>(blk, (float*)d_out);
}